// Round 5
// baseline (776.683 us; speedup 1.0000x reference)
//
#include <hip/hip_runtime.h>

#define B_CNT 4
#define N_CNT 10000
#define E_CNT 100000
#define POST_BLOCKS 400
#define POST_CHUNK 100   // POST_BLOCKS * POST_CHUNK == B_CNT * N_CNT

typedef __attribute__((ext_vector_type(8))) short s16x8;
typedef __attribute__((ext_vector_type(4))) float f32x4;

__device__ __forceinline__ float b2f(unsigned short u) {
  union { unsigned int i; float f; } v; v.i = ((unsigned int)u) << 16; return v.f;
}
__device__ __forceinline__ unsigned short f2b(float f) {  // RNE
  union { float f; unsigned int i; } v; v.f = f;
  unsigned int b = v.i;
  b += 0x7FFFu + ((b >> 16) & 1u);
  return (unsigned short)(b >> 16);
}
__device__ __forceinline__ unsigned short f2b_trunc(float f) {  // 1-op truncation
  union { float f; unsigned int i; } v; v.f = f;
  return (unsigned short)(v.i >> 16);
}

// ---------------------------------------------------------------------------
// K_pre: fused preprocessing.
//   blocks [0,40)   : spectral transform x(4,N,16) -> xnew fp32
//   blocks [40,72)  : pack W1/W2 fp32 -> bf16 (RNE) MFMA B-fragment order
//   blocks [72,463) : per-node in-degree histogram
// ---------------------------------------------------------------------------
__global__ void k_pre(const float* __restrict__ x,
                      const float* __restrict__ tcwr,
                      const float* __restrict__ tcwi,
                      const float* __restrict__ w1,
                      const float* __restrict__ w2,
                      const int* __restrict__ eidx,
                      float* __restrict__ xnew,
                      unsigned short* __restrict__ pw1,
                      unsigned short* __restrict__ pw2,
                      int* __restrict__ cnt) {
  __shared__ float Wr[256], Wi[256];
  const int bid = blockIdx.x;
  const int t = threadIdx.x;

  if (bid < 40) {
    Wr[t] = tcwr[t * 2] + tcwr[t * 2 + 1];   // sum over MODES
    Wi[t] = tcwi[t * 2] + tcwi[t * 2 + 1];
    __syncthreads();
    const int n = bid * 256 + t;
    if (n >= N_CNT) return;
    float xt[4][16];
    for (int tt = 0; tt < 4; ++tt) {
      const float* xp = x + ((size_t)tt * N_CNT + n) * 16;
#pragma unroll
      for (int i0 = 0; i0 < 16; i0 += 4) {
        const float4 v = *(const float4*)(xp + i0);
        xt[tt][i0 + 0] = v.x; xt[tt][i0 + 1] = v.y;
        xt[tt][i0 + 2] = v.z; xt[tt][i0 + 3] = v.w;
      }
    }
    float s[16], a[16], bb[16];
#pragma unroll
    for (int i = 0; i < 16; ++i) {
      s[i]  = xt[0][i] + xt[1][i] + xt[2][i] + xt[3][i];
      a[i]  = xt[0][i] - xt[2][i];
      bb[i] = xt[1][i] - xt[3][i];
    }
    for (int o = 0; o < 16; ++o) {
      float r0 = 0.f, p = 0.f, qq = 0.f;
#pragma unroll
      for (int i = 0; i < 16; ++i) {
        const float wr = Wr[i * 16 + o], wi = Wi[i * 16 + o];
        r0 += s[i] * wr;
        p  += a[i] * wr + bb[i] * wi;
        qq += a[i] * wi - bb[i] * wr;
      }
      xnew[((size_t)0 * N_CNT + n) * 16 + o] = 0.25f * (r0 + 2.f * p);
      xnew[((size_t)1 * N_CNT + n) * 16 + o] = 0.25f * (r0 - 2.f * qq);
      xnew[((size_t)2 * N_CNT + n) * 16 + o] = 0.25f * (r0 - 2.f * p);
      xnew[((size_t)3 * N_CNT + n) * 16 + o] = 0.25f * (r0 + 2.f * qq);
    }
  } else if (bid < 72) {
    const int tg = (bid - 40) * 256 + t;  // 0..8191
    const int tile = tg >> 6, l = tg & 63, q = l >> 4, lm = l & 15;
    if (tile < 32) {
      const int nt = tile >> 2, kk = tile & 3;
      const int n = nt * 16 + lm;
      unsigned short* dst = pw1 + ((size_t)tile * 64 + l) * 8;
#pragma unroll
      for (int j = 0; j < 8; ++j) dst[j] = f2b(w1[(kk * 32 + q * 8 + j) * 128 + n]);
    } else {
      const int t2 = tile - 32;  // 0..95
      const int nt = t2 >> 2, kk = t2 & 3;
      const int n = nt * 16 + lm;
      unsigned short* dst = pw2 + ((size_t)t2 * 64 + l) * 8;
#pragma unroll
      for (int j = 0; j < 8; ++j) dst[j] = f2b(w2[(kk * 32 + q * 8 + j) * 384 + n]);
    }
  } else {
    const int e = (bid - 72) * 256 + t;
    if (e < E_CNT) atomicAdd(&cnt[eidx[E_CNT + e]], 1);
  }
}

// ---------------------------------------------------------------------------
// K_fill: per-block redundant scan of cnt -> rowptr in LDS, then scatter edge
// ids into dst-sorted perm. Block 0 exports rowptr to global for k_post.
// (Replaces the separate single-block k_scan launch.)
// ---------------------------------------------------------------------------
__global__ __launch_bounds__(256) void k_fill(const int* __restrict__ eidx,
                                              const int* __restrict__ cnt,
                                              int* __restrict__ cursor,
                                              int* __restrict__ perm,
                                              int* __restrict__ rowptr_g) {
  __shared__ int rp[N_CNT + 1];
  __shared__ int part[256];
  const int t = threadIdx.x;
  const int base = t * 40;
  int s = 0;
  for (int k = 0; k < 40; ++k) {
    const int idx = base + k;
    s += (idx < N_CNT) ? cnt[idx] : 0;
  }
  part[t] = s;
  __syncthreads();
  for (int off = 1; off < 256; off <<= 1) {
    const int v = (t >= off) ? part[t - off] : 0;
    __syncthreads();
    part[t] += v;
    __syncthreads();
  }
  int run = (t > 0) ? part[t - 1] : 0;
  for (int k = 0; k < 40; ++k) {
    const int idx = base + k;
    if (idx < N_CNT) { rp[idx] = run; run += cnt[idx]; }
  }
  if (t == 255) rp[N_CNT] = part[255];
  __syncthreads();

  const int e = blockIdx.x * 256 + t;
  if (e < E_CNT) {
    const int d = eidx[E_CNT + e];
    const int pos = atomicAdd(&cursor[d], 1);
    perm[rp[d] + pos] = e;
  }
  if (blockIdx.x == 0) {
    for (int idx = t; idx <= N_CNT; idx += 256) rowptr_g[idx] = rp[idx];
  }
}

// ---------------------------------------------------------------------------
// K_edge v5: per block: 32 NATURAL-ORDER edges, one batch. No perm, no atomics.
//   GEMM1: H(32x128) = relu(EA @ W1 + b1)   (MFMA, A sequential, v_perm pack)
//   GEMM2: EW(32x384) = H @ W2 + b2         (MFMA; Hs unions EWs; row-major EW)
//   phase3: messages -> contiguous bf16 store msg[b][e][40]
// LDS ~28.2 KB -> 5 blocks/CU.
// ---------------------------------------------------------------------------
__global__ __launch_bounds__(256, 5) void k_edge(
    const float* __restrict__ ea, const int* __restrict__ eidx,
    const float* __restrict__ esh,
    const unsigned short* __restrict__ pw1, const unsigned short* __restrict__ pw2,
    const float* __restrict__ b1v, const float* __restrict__ b2v,
    const float* __restrict__ xnew, unsigned short* __restrict__ msg) {
  __shared__ __align__(16) unsigned short EWs[32 * 392];  // unions Hs[32*136]
  __shared__ __align__(16) float xgs[32 * 20];            // 16 + 4 pad
  __shared__ float shs[32 * 4];

  const int t = threadIdx.x;
  const int b = blockIdx.y;
  const int e0 = blockIdx.x * 32;
  const int w = t >> 6, l = t & 63, q = l >> 4, lm = l & 15;

  // ---- phase 0: stage xg (single-indirect gather) and sh (contiguous) ----
  if (t < 128) {
    const int el = t >> 2, i0 = (t & 3) * 4;
    const int src = eidx[e0 + el];
    const float4 v = *(const float4*)(xnew + ((size_t)b * N_CNT + src) * 16 + i0);
    xgs[el * 20 + i0 + 0] = v.x;
    xgs[el * 20 + i0 + 1] = v.y;
    xgs[el * 20 + i0 + 2] = v.z;
    xgs[el * 20 + i0 + 3] = v.w;
  } else if (t < 160) {
    const int el = t - 128;
    const float4 v = *(const float4*)(esh + ((size_t)b * E_CNT + e0 + el) * 4);
    shs[el * 4 + 0] = v.x;
    shs[el * 4 + 1] = v.y;
    shs[el * 4 + 2] = v.z;
    shs[el * 4 + 3] = v.w;
  }

  // ---- GEMM1 (A rows sequential in ea) ----
  f32x4 acc1[2][2];
#pragma unroll
  for (int mt = 0; mt < 2; ++mt)
#pragma unroll
    for (int j = 0; j < 2; ++j) acc1[mt][j] = (f32x4)0.0f;

  const float* eab = ea + ((size_t)b * E_CNT + e0) * 128;
  const float* arow[2] = { eab + (size_t)lm * 128,
                           eab + (size_t)(16 + lm) * 128 };
#pragma unroll
  for (int kk = 0; kk < 4; ++kk) {
    const s16x8 bf0 = *(const s16x8*)(pw1 + (((size_t)(2 * w + 0) * 4 + kk) * 64 + l) * 8);
    const s16x8 bf1 = *(const s16x8*)(pw1 + (((size_t)(2 * w + 1) * 4 + kk) * 64 + l) * 8);
#pragma unroll
    for (int mt = 0; mt < 2; ++mt) {
      const unsigned int* ap = (const unsigned int*)(arow[mt] + kk * 32 + q * 8);
      const uint4 a0 = *(const uint4*)ap;
      const uint4 a1 = *(const uint4*)(ap + 4);
      uint4 pk;  // fp32 pairs -> bf16x2 truncation, 1 v_perm / 2 elems
      pk.x = __builtin_amdgcn_perm(a0.y, a0.x, 0x07060302u);
      pk.y = __builtin_amdgcn_perm(a0.w, a0.z, 0x07060302u);
      pk.z = __builtin_amdgcn_perm(a1.y, a1.x, 0x07060302u);
      pk.w = __builtin_amdgcn_perm(a1.w, a1.z, 0x07060302u);
      union { uint4 u; s16x8 v; } cvt; cvt.u = pk;
      acc1[mt][0] = __builtin_amdgcn_mfma_f32_16x16x32_bf16(cvt.v, bf0, acc1[mt][0], 0, 0, 0);
      acc1[mt][1] = __builtin_amdgcn_mfma_f32_16x16x32_bf16(cvt.v, bf1, acc1[mt][1], 0, 0, 0);
    }
  }
  // Hs lives in the first 8704 B of EWs: Hs[m][n] @ EWs[m*136 + n]
#pragma unroll
  for (int j = 0; j < 2; ++j) {
    const int n = (2 * w + j) * 16 + lm;
    const float bias = b1v[n];
#pragma unroll
    for (int mt = 0; mt < 2; ++mt)
#pragma unroll
      for (int r = 0; r < 4; ++r) {
        const float v = fmaxf(acc1[mt][j][r] + bias, 0.0f);
        EWs[(mt * 16 + q * 4 + r) * 136 + n] = f2b_trunc(v);
      }
  }
  __syncthreads();  // barrier 1: Hs ready

  // ---- GEMM2 (A from Hs region) ----
  f32x4 acc2[2][6];
#pragma unroll
  for (int mt = 0; mt < 2; ++mt)
#pragma unroll
    for (int jj = 0; jj < 6; ++jj) acc2[mt][jj] = (f32x4)0.0f;

#pragma unroll
  for (int kk = 0; kk < 4; ++kk) {
    s16x8 bw[6];
#pragma unroll
    for (int jj = 0; jj < 6; ++jj)
      bw[jj] = *(const s16x8*)(pw2 + (((size_t)(6 * w + jj) * 4 + kk) * 64 + l) * 8);
#pragma unroll
    for (int mt = 0; mt < 2; ++mt) {
      const s16x8 ah = *(const s16x8*)(&EWs[(mt * 16 + lm) * 136 + kk * 32 + q * 8]);
#pragma unroll
      for (int jj = 0; jj < 6; ++jj)
        acc2[mt][jj] = __builtin_amdgcn_mfma_f32_16x16x32_bf16(ah, bw[jj], acc2[mt][jj], 0, 0, 0);
    }
  }
  __syncthreads();  // barrier 2: Hs reads done; EWs region may be overwritten

  // ---- EW epilogue: row-major store ----
#pragma unroll
  for (int jj = 0; jj < 6; ++jj) {
    const int n2 = (6 * w + jj) * 16 + lm;
    const float bias = b2v[n2];
#pragma unroll
    for (int mt = 0; mt < 2; ++mt)
#pragma unroll
      for (int r = 0; r < 4; ++r)
        EWs[(mt * 16 + q * 4 + r) * 392 + n2] = f2b_trunc(acc2[mt][jj][r] + bias);
  }
  __syncthreads();  // barrier 3: EW ready

  // ---- phase 3: messages, contiguous bf16 store (8 threads/edge, 5 ch) ----
  {
    const int m = t >> 3;
    const int sub = t & 7;
    float xr[16];
#pragma unroll
    for (int i0 = 0; i0 < 16; i0 += 4) {
      const float4 v = *(const float4*)(&xgs[m * 20 + i0]);
      xr[i0 + 0] = v.x; xr[i0 + 1] = v.y; xr[i0 + 2] = v.z; xr[i0 + 3] = v.w;
    }
    const float sh0v = shs[m * 4 + 0];
    unsigned short* mp = msg + ((size_t)b * E_CNT + e0 + m) * 40;
    const int c0 = sub * 5;
#pragma unroll
    for (int cc = 0; cc < 5; ++cc) {
      const int c = c0 + cc;
      float accv = 0.0f, mul;
      if (c < 16) {
        const unsigned short* ep = &EWs[m * 392 + c];
#pragma unroll
        for (int i = 0; i < 16; ++i) accv += xr[i] * b2f(ep[i * 16]);
        mul = 0.25f * sh0v;  // ALPHA = 1/sqrt(16)
      } else {
        const int cr = c - 16;
        const int oo = cr / 3;
        const int md = cr - oo * 3;
        const unsigned short* ep = &EWs[m * 392 + 256 + oo];
#pragma unroll
        for (int i = 0; i < 16; ++i) accv += xr[i] * b2f(ep[i * 8]);
        mul = 0.25f * shs[m * 4 + 1 + md];
      }
      mp[c] = f2b(accv * mul);
    }
  }
}

// ---------------------------------------------------------------------------
// K_post: fused aggregate + BN stats + normalize, single launch with software
// grid barrier. 400 blocks co-resident by construction (small LDS/VGPR ->
// >=2 blocks/CU, 400 < 512). bar zeroed by the memset every call.
// ---------------------------------------------------------------------------
__global__ __launch_bounds__(256) void k_post(
    const unsigned short* __restrict__ msg, const int* __restrict__ rowptr,
    const int* __restrict__ perm, const float* __restrict__ gma,
    const float* __restrict__ bta, float* __restrict__ aggbuf,
    float* psum, float* psq, int* bar, float* __restrict__ outp) {
  __shared__ float rs[240], rq[240];
  __shared__ float scs[40], shf[40];
  const int t = threadIdx.x;
  const int sub = t / 40, c = t - sub * 40;  // valid for t<240

  if (t < 240) {
    float bs = 0.f, bq = 0.f;
    for (int j = 0; j < 17; ++j) {
      const int pl = j * 6 + sub;
      const int p = blockIdx.x * POST_CHUNK + pl;
      if (pl < POST_CHUNK && p < B_CNT * N_CNT) {
        const int b = p / N_CNT, n = p - b * N_CNT;
        const int r0 = rowptr[n], r1 = rowptr[n + 1];
        float acc = 0.f;
        const unsigned short* mb = msg + (size_t)b * E_CNT * 40 + c;
        for (int k = r0; k < r1; ++k) acc += b2f(mb[(size_t)perm[k] * 40]);
        const float v = acc / fmaxf((float)(r1 - r0), 1.f);
        aggbuf[(size_t)p * 40 + c] = v;
        bs += v; bq += v * v;
      }
    }
    rs[t] = bs; rq[t] = bq;
  }
  __syncthreads();
  if (t < 40) {
    float s0 = 0.f, q0 = 0.f;
#pragma unroll
    for (int j2 = 0; j2 < 6; ++j2) { s0 += rs[j2 * 40 + t]; q0 += rq[j2 * 40 + t]; }
    atomicAdd(&psum[t], s0);
    atomicAdd(&psq[t], q0);
  }
  // ---- software grid barrier ----
  __threadfence();
  __syncthreads();
  if (t == 0) {
    atomicAdd(bar, 1);
    while (atomicAdd(bar, 0) < POST_BLOCKS) __builtin_amdgcn_s_sleep(2);
  }
  __syncthreads();
  // ---- phase B: finalize + normalize own slice ----
  if (t < 40) {
    const float inv = 1.0f / (float)(B_CNT * N_CNT);
    const float su = atomicAdd(&psum[t], 0.0f);   // coherent read
    const float sq = atomicAdd(&psq[t], 0.0f);
    const float mu = su * inv;
    const float var = fmaxf(sq * inv - mu * mu, 0.f);
    const float sc = rsqrtf(var + 1e-5f) * gma[t];
    scs[t] = sc;
    shf[t] = bta[t] - mu * sc;
  }
  __syncthreads();
  if (t < 240) {
    const float sc = scs[c], sh = shf[c];
    for (int j = 0; j < 17; ++j) {
      const int pl = j * 6 + sub;
      const int p = blockIdx.x * POST_CHUNK + pl;
      if (pl < POST_CHUNK && p < B_CNT * N_CNT)
        outp[(size_t)p * 40 + c] = aggbuf[(size_t)p * 40 + c] * sc + sh;
    }
  }
}

// ---------------------------------------------------------------------------
// Workspace layout (bytes), total ~41.7 MB:
//   [0)            msg      32,000,000   (bf16, natural edge order)
//   [32,000,000)   xnew      2,560,000
//   [34,560,000)   pw1          32,768
//   [34,592,768)   pw2          98,304
//   [34,691,072)   aggbuf    6,400,000
//   [41,091,072)   rowptr       40,016  (padded to 41,131,088)
//   [41,131,088)   cnt          40,000  (zeroed)
//   [41,171,088)   cursor       40,000  (zeroed)
//   [41,211,088)   psum            160  (zeroed)
//   [41,211,248)   psq             160  (zeroed)
//   [41,211,408)   bar              16  (zeroed)
//   [41,211,424)   perm        400,000
// ---------------------------------------------------------------------------
extern "C" void kernel_launch(void* const* d_in, const int* in_sizes, int n_in,
                              void* d_out, int out_size, void* d_ws, size_t ws_size,
                              hipStream_t stream) {
  (void)in_sizes; (void)n_in; (void)out_size; (void)ws_size;
  const float* x    = (const float*)d_in[0];
  const int*   eidx = (const int*)d_in[1];
  const float* ea   = (const float*)d_in[2];
  const float* esh  = (const float*)d_in[3];
  const float* tcwr = (const float*)d_in[4];
  const float* tcwi = (const float*)d_in[5];
  const float* w1   = (const float*)d_in[6];
  const float* b1   = (const float*)d_in[7];
  const float* w2   = (const float*)d_in[8];
  const float* b2   = (const float*)d_in[9];
  const float* gma  = (const float*)d_in[10];
  const float* bta  = (const float*)d_in[11];

  char* ws = (char*)d_ws;
  unsigned short* msg    = (unsigned short*)(ws + 0);
  float*          xnew   = (float*)(ws + 32000000);
  unsigned short* pw1    = (unsigned short*)(ws + 34560000);
  unsigned short* pw2    = (unsigned short*)(ws + 34592768);
  float*          aggbuf = (float*)(ws + 34691072);
  int*            rowptr = (int*)(ws + 41091072);
  int*            cnt    = (int*)(ws + 41131088);
  int*            cursor = (int*)(ws + 41171088);
  float*          psum   = (float*)(ws + 41211088);
  float*          psq    = (float*)(ws + 41211248);
  int*            bar    = (int*)(ws + 41211408);
  int*            perm   = (int*)(ws + 41211424);

  hipMemsetAsync(ws + 41131088, 0, 80336, stream);  // cnt+cursor+psum+psq+bar
  k_pre<<<dim3(463), dim3(256), 0, stream>>>(x, tcwr, tcwi, w1, w2, eidx,
                                             xnew, pw1, pw2, cnt);
  k_edge<<<dim3(E_CNT / 32, B_CNT), dim3(256), 0, stream>>>(
      ea, eidx, esh, pw1, pw2, b1, b2, xnew, msg);
  k_fill<<<dim3(391), dim3(256), 0, stream>>>(eidx, cnt, cursor, perm, rowptr);
  k_post<<<dim3(POST_BLOCKS), dim3(256), 0, stream>>>(
      msg, rowptr, perm, gma, bta, aggbuf, psum, psq, bar, (float*)d_out);
}